// Round 18
// baseline (258.209 us; speedup 1.0000x reference)
//
#include <hip/hip_runtime.h>
#include <hip/hip_bf16.h>

#define SPAN_SHIFT 8      // dst-bucket span = 256 nodes
#define BCAP 8192         // per-bucket tmp capacity (mean ~4080, >60 sigma safety)

typedef __attribute__((ext_vector_type(8))) short short8;
typedef __attribute__((ext_vector_type(4))) float float4v;

// ---------- bf16 helpers (OCP bf16 = fp32 upper 16 bits) ----------
__device__ __forceinline__ float bf2f(unsigned short u) {
  union { unsigned int i; float f; } v; v.i = ((unsigned int)u) << 16; return v.f;
}
__device__ __forceinline__ unsigned short f2bf(float f) {
  union { float f; unsigned int i; } v; v.f = f;
  unsigned int x = v.i;
  return (unsigned short)((x + 0x7fffu + ((x >> 16) & 1u)) >> 16);  // RNE
}

// ---------- 0. dtype probes + W pre-swizzle (self-probed) + zero bcnt/acc/ctr ----------
// flags[0]=x_fp32 flags[1]=int64 flags[4]=b1_fp32 flags[5]=b2_fp32
// blocks: 0..3 probes, 4..131 swizzle (W1:4..67, W2:68..131), 132.. zeroing
__global__ __launch_bounds__(256) void detect_swz_zero_k(
    const unsigned short* __restrict__ xu,  const int* __restrict__ ei,
    const unsigned short* __restrict__ b1u, const unsigned short* __restrict__ b2u,
    const void* __restrict__ W1, const void* __restrict__ W2,
    unsigned short* __restrict__ w1s, unsigned short* __restrict__ w2s,
    int* __restrict__ flags, int* __restrict__ bcnt, float* __restrict__ acc,
    int NBKT, int GP) {
  const int b = blockIdx.x;
  const int tid = threadIdx.x;
  if (b >= 132) {                                 // zeroing blocks
    int base = (b - 132) * 4096 + tid;
    #pragma unroll
    for (int j = 0; j < 16; ++j) {
      int i = base + j * 256;
      if (i < NBKT) bcnt[i] = 0;
      else if (i < NBKT + GP) acc[i - NBKT] = 0.f;   // includes pool done-counter slot
    }
    return;
  }
  __shared__ int s_cnt;
  if (tid == 0) s_cnt = 0;
  __syncthreads();
  if (b >= 4) {                                   // swizzle blocks, self-probe W dtype
    const void* Wraw = (b < 68) ? W1 : W2;
    unsigned short* out = (b < 68) ? w1s : w2s;
    const unsigned short* Wu = (const unsigned short*)Wraw;
    int c = 0;
    for (int i = tid; i < 512; i += 256) {
      int e = (Wu[i] >> 7) & 0xFF;
      if (e < 96 || e > 159) c++;                 // fp32 halves look wild as bf16
    }
    atomicAdd(&s_cnt, c);
    __syncthreads();
    const int wf32 = s_cnt > 64;
    int u = ((b - 4) & 63) * 256 + tid;           // 0..16383
    int j = u & 7, lane = (u >> 3) & 63, blk = u >> 9;
    int cc = blk >> 3, t = blk & 7;
    int quad = lane >> 4, col = lane & 15;
    int k = cc * 32 + quad * 8 + j;
    int n = t * 16 + col;
    out[u] = wf32 ? f2bf(((const float*)Wraw)[k * 128 + n])
                  : ((const unsigned short*)Wraw)[k * 128 + n];
    return;
  }
  int cnt = 0;
  if (b == 1) {  // int width: high words of int64 positives are all zero
    for (int i = tid; i < 4096; i += 256)
      if (ei[2 * i + 1] == 0) cnt++;
    atomicAdd(&s_cnt, cnt);
    __syncthreads();
    if (tid == 0) flags[1] = (s_cnt > 2048) ? 1 : 0;
    return;
  }
  const unsigned short* p; int n; int fi;
  if (b == 0)      { p = xu;  n = 16384; fi = 0; }
  else if (b == 2) { p = b1u; n = 128;   fi = 4; }
  else             { p = b2u; n = 128;   fi = 5; }
  for (int i = tid; i < n; i += 256) {
    int e = (p[i] >> 7) & 0xFF;
    if (e < 96 || e > 159) cnt++;
  }
  atomicAdd(&s_cnt, cnt);
  __syncthreads();
  if (tid == 0) flags[fi] = (s_cnt * 8 > n) ? 1 : 0;
}

// ---------- shared GEMM body (W pre-swizzled; LDS-staged coalesced C-store) ----------
__device__ __forceinline__ void gemm_body(const void* __restrict__ X,
                                          const unsigned short* __restrict__ Wsw,
                                          unsigned short* __restrict__ XWb, int N,
                                          int xf32, int row0,
                                          unsigned short* Wl, unsigned short* Xl) {
  const int tid = threadIdx.x;
  for (int v = tid; v < 2048; v += 256)           // W: linear conflict-free copy
    ((short8*)Wl)[v] = ((const short8*)Wsw)[v];
  for (int v = tid; v < 2048; v += 256) {         // X: 64 rows x 128, bf16, pad +8
    int r = v >> 5, k4 = (v & 31) * 4;
    int row = row0 + r;
    ushort4 u = make_ushort4(0, 0, 0, 0);
    if (row < N) {
      long long gi = (long long)row * 128 + k4;
      if (xf32) {
        float4 xv = *(const float4*)&((const float*)X)[gi];
        u.x = f2bf(xv.x); u.y = f2bf(xv.y); u.z = f2bf(xv.z); u.w = f2bf(xv.w);
      } else {
        u = *(const ushort4*)&((const unsigned short*)X)[gi];
      }
    }
    *(ushort4*)&Xl[r * 136 + k4] = u;
  }
  __syncthreads();
  const int w = tid >> 6, lane = tid & 63;
  const int quad = lane >> 4, col = lane & 15;
  float4v acc[8];
  #pragma unroll
  for (int t = 0; t < 8; ++t) acc[t] = (float4v){0.f, 0.f, 0.f, 0.f};
  #pragma unroll
  for (int c = 0; c < 4; ++c) {
    short8 a = *(const short8*)&Xl[(w * 16 + col) * 136 + c * 32 + quad * 8];
    #pragma unroll
    for (int t = 0; t < 8; ++t) {
      short8 b = *(const short8*)&Wl[((c * 8 + t) * 64 + lane) * 8];
      acc[t] = __builtin_amdgcn_mfma_f32_16x16x32_bf16(a, b, acc[t], 0, 0, 0);
    }
  }
  // C-store via own 16-row LDS region, then coalesced 16-B copy-out
  #pragma unroll
  for (int t = 0; t < 8; ++t) {
    #pragma unroll
    for (int r = 0; r < 4; ++r)
      Xl[(w * 16 + quad * 4 + r) * 136 + t * 16 + col] = f2bf(acc[t][r]);
  }
  __syncthreads();
  for (int v = tid; v < 1024; v += 256) {
    int r = v >> 4, ck = (v & 15) * 8;
    int row = row0 + r;
    if (row < N)
      *(short8*)&XWb[(long long)row * 128 + ck] = *(const short8*)&Xl[r * 136 + ck];
  }
}

// ---------- 1. fused: scatterA (blocks < SA) + gemm1 (blocks >= SA) ----------
__global__ __launch_bounds__(256) void scatA_gemm1_k(const int* __restrict__ ei,
    int* __restrict__ bcnt, int2* __restrict__ tmp, int E, int SA,
    const void* __restrict__ X, const unsigned short* __restrict__ Wsw,
    unsigned short* __restrict__ XWb, int N,
    const int* __restrict__ flags, int NBKT) {
  __shared__ __align__(16) char smem[50688];
  const int tid = threadIdx.x;
  if ((int)blockIdx.x >= SA) {                    // gemm1 blocks
    unsigned short* Wl = (unsigned short*)smem;           // 32 KB
    unsigned short* Xl = (unsigned short*)(smem + 32768); // 17.4 KB
    gemm_body(X, Wsw, XWb, N, flags[0], ((int)blockIdx.x - SA) * 64, Wl, Xl);
    return;
  }
  // ---- scatterA body ----
  int2* stage = (int2*)smem;                      // 32 KB
  int* hist  = (int*)(smem + 32768);
  int* off   = hist + 256;
  int* cnt2  = off + 256;
  int* gbase = cnt2 + 256;
  int* wsum  = gbase + 256;
  hist[tid] = 0; cnt2[tid] = 0;
  __syncthreads();
  const int base = blockIdx.x * 4096;
  const int i64 = flags[1];
  int rs[16], rd[16];
  #pragma unroll
  for (int j = 0; j < 16; ++j) {
    int e = base + j * 256 + tid;
    if (e < E) {
      int s, d;
      if (i64) { s = ei[2 * e]; d = ei[2 * (E + e)]; }
      else     { s = ei[e];     d = ei[E + e]; }
      rs[j] = s; rd[j] = d;
      atomicAdd(&hist[d >> SPAN_SHIFT], 1);
    } else rd[j] = -1;
  }
  __syncthreads();
  {
    int lane = tid & 63, w = tid >> 6;
    int v = hist[tid], inc = v;
    #pragma unroll
    for (int o = 1; o < 64; o <<= 1) { int n = __shfl_up(inc, o, 64); if (lane >= o) inc += n; }
    if (lane == 63) wsum[w] = inc;
    __syncthreads();
    int pre = 0;
    #pragma unroll
    for (int k = 0; k < 4; ++k) if (k < w) pre += wsum[k];
    off[tid] = pre + inc - v;
  }
  __syncthreads();
  #pragma unroll
  for (int j = 0; j < 16; ++j) {
    if (rd[j] >= 0) {
      int b = rd[j] >> SPAN_SHIFT;
      int r = atomicAdd(&cnt2[b], 1);
      int2 rec; rec.x = rs[j]; rec.y = rd[j];
      stage[off[b] + r] = rec;
    }
  }
  if (tid < NBKT && hist[tid] > 0)
    gbase[tid] = tid * BCAP + atomicAdd(&bcnt[tid], hist[tid]);
  __syncthreads();
  const int total = off[255] + hist[255];
  for (int i = tid; i < total; i += 256) {
    int2 rec = stage[i];
    int b = rec.y >> SPAN_SHIFT;
    tmp[gbase[b] + (i - off[b])] = rec;
  }
}

// ---------- generic GEMM (xmode: 1 = fp32 input, 2 = bf16 input) ----------
__global__ __launch_bounds__(256) void gemm_k(const void* __restrict__ X,
                                              const unsigned short* __restrict__ Wsw,
                                              unsigned short* __restrict__ XWb, int N,
                                              int xmode) {
  __shared__ __align__(16) unsigned short Wl[16384];
  __shared__ __align__(16) unsigned short Xl[64 * 136];
  gemm_body(X, Wsw, XWb, N, (xmode == 1) ? 1 : 0, blockIdx.x * 64, Wl, Xl);
}

// ---------- 2. scatB (1024 threads): hist -> rowptr+dinv -> place ----------
__global__ __launch_bounds__(1024) void scatB_k(const int2* __restrict__ tmp,
    const int* __restrict__ bcnt, int* __restrict__ rowptr,
    float* __restrict__ dinv, int* __restrict__ spk, int N, int NBKT, int E) {
  __shared__ int hist[256];
  __shared__ int pfx[256];
  __shared__ int cur[256];
  __shared__ int ws[4];
  const int tid = threadIdx.x;
  const int b = blockIdx.x;
  const int lane = tid & 63, w = tid >> 6;
  // global prefix over bucket counts (first 256 threads; 196 ints, L2-hot)
  int c = (tid < 256 && tid < NBKT) ? bcnt[tid] : 0;
  if (tid < 256) hist[tid] = 0;
  {
    int inc = c;
    #pragma unroll
    for (int o = 1; o < 64; o <<= 1) { int n = __shfl_up(inc, o, 64); if (lane >= o) inc += n; }
    if (tid < 256 && lane == 63) ws[w] = inc;
    __syncthreads();
    if (tid < 256) {
      int pre = 0;
      #pragma unroll
      for (int k = 0; k < 4; ++k) if (k < w) pre += ws[k];
      pfx[tid] = pre + inc - c;
    }
  }
  __syncthreads();
  const int bbase = pfx[b];
  const int cnt = bcnt[b];
  const int2* src = tmp + (long long)b * BCAP;
  for (int i = tid; i < cnt; i += 1024)
    atomicAdd(&hist[src[i].y & 255], 1);
  __syncthreads();
  // node-level scan (first 256 threads)
  int v = (tid < 256) ? hist[tid] : 0;
  {
    int inc = v;
    #pragma unroll
    for (int o = 1; o < 64; o <<= 1) { int n = __shfl_up(inc, o, 64); if (lane >= o) inc += n; }
    if (tid < 256 && lane == 63) ws[w] = inc;
    __syncthreads();
    if (tid < 256) {
      int pre = 0;
      #pragma unroll
      for (int k = 0; k < 4; ++k) if (k < w) pre += ws[k];
      const int start = bbase + pre + inc - v;
      int node = (b << SPAN_SHIFT) + tid;
      if (node < N) {
        rowptr[node] = start;
        dinv[node] = rsqrtf((float)(v + 1));   // +1 self-loop
      }
      cur[tid] = start;
    }
  }
  if (b == 0 && tid == 0) rowptr[N] = E;
  __syncthreads();
  for (int i = tid; i < cnt; i += 1024) {   // place (src-only payload)
    int2 rec = src[i];
    int pos = atomicAdd(&cur[rec.y & 255], 1);
    spk[pos] = rec.x;
  }
}

// ---------- 3. aggregate: quarter-wave gathers + cooperative index preload ----------
__global__ __launch_bounds__(256) void aggregate_k(const unsigned short* __restrict__ XWb,
    const int* __restrict__ rowptr, const int* __restrict__ spk,
    const float* __restrict__ dinv, const void* __restrict__ bias_raw, int bias_fi,
    void* __restrict__ H, int N, int relu, int out_bf16,
    const int* __restrict__ flags) {
  int wid = (blockIdx.x * 256 + threadIdx.x) >> 6;  // one wave per node
  if (wid >= N) return;
  const int lane = threadIdx.x & 63;
  const int q = lane >> 4;           // quarter: which edge of the group
  const int fl = (lane & 15) * 8;    // 8 features per lane
  const int beg = rowptr[wid], end = rowptr[wid + 1];
  const int deg = end - beg;
  const float di = dinv[wid];
  float a[8];
  #pragma unroll
  for (int j = 0; j < 8; ++j) a[j] = 0.f;
  for (int base = 0; base < deg; base += 64) {
    const int rem = min(deg - base, 64);              // wave-uniform
    const int li = base + lane;
    const int sil = spk[beg + min(li, deg - 1)];      // ONE coalesced load (clamped)
    const float wl = (li < deg) ? dinv[sil] : 0.f;    // ONE gather
    const int ngroups = (rem + 3) >> 2;               // wave-uniform, <= 16
    int g = 0;
    for (; g + 4 <= ngroups; g += 4) {                // 16 edges per iteration
      int e0 = (g + 0) * 4 + q, e1 = (g + 1) * 4 + q;
      int e2 = (g + 2) * 4 + q, e3 = (g + 3) * 4 + q;
      int   s0 = __shfl(sil, e0, 64), s1 = __shfl(sil, e1, 64);
      int   s2 = __shfl(sil, e2, 64), s3 = __shfl(sil, e3, 64);
      float w0 = __shfl(wl, e0, 64),  w1 = __shfl(wl, e1, 64);
      float w2 = __shfl(wl, e2, 64),  w3 = __shfl(wl, e3, 64);
      short8 u0 = *(const short8*)&XWb[(long long)s0 * 128 + fl];
      short8 u1 = *(const short8*)&XWb[(long long)s1 * 128 + fl];
      short8 u2 = *(const short8*)&XWb[(long long)s2 * 128 + fl];
      short8 u3 = *(const short8*)&XWb[(long long)s3 * 128 + fl];
      #pragma unroll
      for (int j = 0; j < 8; ++j)
        a[j] += w0 * bf2f((unsigned short)u0[j]) + w1 * bf2f((unsigned short)u1[j])
              + w2 * bf2f((unsigned short)u2[j]) + w3 * bf2f((unsigned short)u3[j]);
    }
    if (g + 2 <= ngroups) {                           // 8-edge tail
      int e0 = (g + 0) * 4 + q, e1 = (g + 1) * 4 + q;
      int   s0 = __shfl(sil, e0, 64), s1 = __shfl(sil, e1, 64);
      float w0 = __shfl(wl, e0, 64),  w1 = __shfl(wl, e1, 64);
      short8 u0 = *(const short8*)&XWb[(long long)s0 * 128 + fl];
      short8 u1 = *(const short8*)&XWb[(long long)s1 * 128 + fl];
      #pragma unroll
      for (int j = 0; j < 8; ++j)
        a[j] += w0 * bf2f((unsigned short)u0[j]) + w1 * bf2f((unsigned short)u1[j]);
      g += 2;
    }
    if (g < ngroups) {                                // 4-edge tail
      int e0 = g * 4 + q;
      int   s0 = __shfl(sil, e0, 64);
      float w0 = __shfl(wl, e0, 64);
      short8 u0 = *(const short8*)&XWb[(long long)s0 * 128 + fl];
      #pragma unroll
      for (int j = 0; j < 8; ++j)
        a[j] += w0 * bf2f((unsigned short)u0[j]);
    }
  }
  #pragma unroll
  for (int j = 0; j < 8; ++j) {       // cross-quarter reduce
    a[j] += __shfl_xor(a[j], 16, 64);
    a[j] += __shfl_xor(a[j], 32, 64);
  }
  if (q == 0) {
    short8 su = *(const short8*)&XWb[(long long)wid * 128 + fl];
    float d2 = di * di;
    float o[8];
    #pragma unroll
    for (int j = 0; j < 8; ++j)
      o[j] = di * a[j] + d2 * bf2f((unsigned short)su[j]);
    if (bias_fi >= 0) {
      if (flags[bias_fi]) {
        const float* bf = (const float*)bias_raw;
        float4 b0 = *(const float4*)&bf[fl];
        float4 b1 = *(const float4*)&bf[fl + 4];
        o[0] += b0.x; o[1] += b0.y; o[2] += b0.z; o[3] += b0.w;
        o[4] += b1.x; o[5] += b1.y; o[6] += b1.z; o[7] += b1.w;
      } else {
        const unsigned short* bu = (const unsigned short*)bias_raw;
        #pragma unroll
        for (int j = 0; j < 8; ++j) o[j] += bf2f(bu[fl + j]);
      }
    }
    if (relu) {
      #pragma unroll
      for (int j = 0; j < 8; ++j) o[j] = fmaxf(o[j], 0.f);
    }
    if (out_bf16) {
      short8 uo;
      #pragma unroll
      for (int j = 0; j < 8; ++j) uo[j] = (short)f2bf(o[j]);
      *(short8*)&((unsigned short*)H)[(long long)wid * 128 + fl] = uo;
    } else {
      float* Hf = (float*)H;
      *(float4*)&Hf[(long long)wid * 128 + fl]     = make_float4(o[0], o[1], o[2], o[3]);
      *(float4*)&Hf[(long long)wid * 128 + fl + 4] = make_float4(o[4], o[5], o[6], o[7]);
    }
  }
}

// ---------- 4. pool: per-wave run-length partials + last-block finalize ----------
__global__ __launch_bounds__(256) void pool_k(const unsigned short* __restrict__ H,
    const int* __restrict__ batch, float* __restrict__ acc, int* __restrict__ ctr,
    const void* __restrict__ B2raw, float* __restrict__ out, int N, int G,
    const int* __restrict__ flags) {
  const int i64 = flags[1];
  const int lane = threadIdx.x & 63;
  const int w = threadIdx.x >> 6;
  const int chunk = (N + gridDim.x - 1) / gridDim.x;
  const int bstart = blockIdx.x * chunk;
  const int bend = min(bstart + chunk, N);
  const int sub = (chunk + 3) / 4;
  const int s = bstart + w * sub;
  const int e = min(s + sub, bend);
  if (s < e) {
    float ax = 0.f, ay = 0.f;
    int curg = i64 ? batch[2 * s] : batch[s];
    for (int n = s; n < e; ++n) {
      int g = i64 ? batch[2 * n] : batch[n];
      if (g != curg) {
        atomicAdd(&acc[curg * 128 + lane * 2], ax);
        atomicAdd(&acc[curg * 128 + lane * 2 + 1], ay);
        ax = ay = 0.f; curg = g;
      }
      ushort2 v = *(const ushort2*)&H[(long long)n * 128 + lane * 2];
      ax += bf2f(v.x); ay += bf2f(v.y);
    }
    atomicAdd(&acc[curg * 128 + lane * 2], ax);
    atomicAdd(&acc[curg * 128 + lane * 2 + 1], ay);
  }
  // last-arriving block finalizes (no dispatch-order assumption)
  __threadfence();
  __shared__ int s_last;
  __shared__ int gb[65];     // G <= 64 here
  if (threadIdx.x == 0)
    s_last = (atomicAdd(ctr, 1) == (int)gridDim.x - 1) ? 1 : 0;
  __syncthreads();
  if (!s_last) return;
  for (int t = threadIdx.x; t <= G; t += 256) {
    int lo = 0, hi = N;
    while (lo < hi) {
      int mid = (lo + hi) >> 1;
      int bv = i64 ? batch[2 * mid] : batch[mid];
      if (bv < t) lo = mid + 1; else hi = mid;
    }
    gb[t] = lo;
  }
  __syncthreads();
  const int tot = G * 128;
  for (int i = threadIdx.x; i < tot; i += 256) {
    int g = i >> 7, f = i & 127;
    int cnt = gb[g + 1] - gb[g];
    float sum = atomicAdd(&acc[i], 0.f);   // device-scope coherent read
    float b2 = flags[5] ? ((const float*)B2raw)[f]
                        : bf2f(((const unsigned short*)B2raw)[f]);
    out[i] = (cnt > 0) ? (sum / (float)cnt + b2) : 0.f;
  }
}

extern "C" void kernel_launch(void* const* d_in, const int* in_sizes, int n_in,
                              void* d_out, int out_size, void* d_ws, size_t ws_size,
                              hipStream_t stream) {
  const int N = in_sizes[0] / 128;   // 50000
  const int E = in_sizes[1] / 2;     // 800000
  const int G = out_size / 128;      // 64
  const int NB = (N + 255) >> SPAN_SHIFT;  // dst buckets (196), <=256
  const int GB = (N + 63) / 64;            // gemm blocks
  const int SA = (E + 4095) / 4096;        // scatterA blocks
  const int GP = G * 128 + 1;              // acc + done-counter slot
  const int ZB = (NB + GP + 4095) / 4096;  // zeroing blocks

  const void* X  = d_in[0];
  const int*  EI = (const int*)d_in[1];
  const int*  BA = (const int*)d_in[2];
  const void* W1 = d_in[3];
  const void* B1 = d_in[4];
  const void* W2 = d_in[5];
  const void* B2 = d_in[6];
  float* OUT = (float*)d_out;

  char* ws = (char*)d_ws;
  size_t o = 0;
  auto alloc = [&](size_t b) { size_t r = o; o += (b + 255) & ~(size_t)255; return r; };
  int*   flags  = (int*)(ws + alloc(256));
  unsigned short* w1s = (unsigned short*)(ws + alloc(16384 * 2));  // pre-swizzled bf16
  unsigned short* w2s = (unsigned short*)(ws + alloc(16384 * 2));
  float* acc    = (float*)(ws + alloc((size_t)GP * 4));   // G*128 sums + ctr
  int*   ctr    = (int*)&acc[G * 128];
  int*   bcnt   = (int*)(ws + alloc(256 * 4));
  int*   rowptr = (int*)(ws + alloc((size_t)(N + 1) * 4));
  int*   spk    = (int*)(ws + alloc((size_t)E * 4));      // src-only payload
  float* dinv   = (float*)(ws + alloc((size_t)N * 4));
  unsigned short* xwb = (unsigned short*)(ws + alloc((size_t)N * 128 * 2));
  char*  hreg   = ws + alloc((size_t)N * 128 * 4);  // 25.6 MB multi-use region
  unsigned short* h1b = (unsigned short*)hreg;      // layer-1 H, bf16 (12.8 MB)
  unsigned short* h2b = (unsigned short*)hreg;      // layer-2 H, bf16 (12.8 MB)
  int2*  tmp    = (int2*)hreg;                      // bucket regions 12.85 MB; dead before aggregate1

  // 1. probes + W pre-swizzle + zeroing (one launch)
  detect_swz_zero_k<<<132 + ZB, 256, 0, stream>>>(
      (const unsigned short*)X, EI,
      (const unsigned short*)B1, (const unsigned short*)B2,
      W1, W2, w1s, w2s, flags, bcnt, acc, NB, GP);
  // 2. fused scatterA + gemm1
  scatA_gemm1_k<<<SA + GB, 256, 0, stream>>>(EI, bcnt, tmp, E, SA,
                                             X, w1s, xwb, N, flags, NB);
  // 3. CSR finish (single merged kernel, 1024 threads)
  scatB_k<<<NB, 1024, 0, stream>>>(tmp, bcnt, rowptr, dinv, spk, N, NB, E);

  dim3 agrid((N * 64 + 255) / 256);
  // layer 1 aggregate (bf16 out; tmp is dead now)
  aggregate_k<<<agrid, 256, 0, stream>>>(xwb, rowptr, spk, dinv, B1, 4,
                                         h1b, N, 1, 1, flags);
  // layer 2
  gemm_k<<<GB, 256, 0, stream>>>(h1b, w2s, xwb, N, 2);
  aggregate_k<<<agrid, 256, 0, stream>>>(xwb, rowptr, spk, dinv, (const void*)nullptr, -1,
                                         h2b, N, 0, 1, flags);
  // pool (single launch, last-block finalize)
  pool_k<<<512, 256, 0, stream>>>(h2b, BA, acc, ctr, B2, OUT, N, G, flags);
}

// Round 19
// 215.704 us; speedup vs baseline: 1.1970x; 1.1970x over previous
//
#include <hip/hip_runtime.h>
#include <hip/hip_bf16.h>

#define SPAN_SHIFT 8      // dst-bucket span = 256 nodes
#define BCAP 8192         // per-bucket tmp capacity (mean ~4080, >60 sigma safety)

typedef __attribute__((ext_vector_type(8))) short short8;
typedef __attribute__((ext_vector_type(4))) float float4v;

// ---------- bf16 helpers (OCP bf16 = fp32 upper 16 bits) ----------
__device__ __forceinline__ float bf2f(unsigned short u) {
  union { unsigned int i; float f; } v; v.i = ((unsigned int)u) << 16; return v.f;
}
__device__ __forceinline__ unsigned short f2bf(float f) {
  union { float f; unsigned int i; } v; v.f = f;
  unsigned int x = v.i;
  return (unsigned short)((x + 0x7fffu + ((x >> 16) & 1u)) >> 16);  // RNE
}

// ---------- 0. dtype probes + W pre-swizzle (self-probed) + zero bcnt/acc ----------
// flags[0]=x_fp32 flags[1]=int64 flags[4]=b1_fp32 flags[5]=b2_fp32
// blocks: 0..3 probes, 4..131 swizzle (W1:4..67, W2:68..131), 132.. zeroing
__global__ __launch_bounds__(256) void detect_swz_zero_k(
    const unsigned short* __restrict__ xu,  const int* __restrict__ ei,
    const unsigned short* __restrict__ b1u, const unsigned short* __restrict__ b2u,
    const void* __restrict__ W1, const void* __restrict__ W2,
    unsigned short* __restrict__ w1s, unsigned short* __restrict__ w2s,
    int* __restrict__ flags, int* __restrict__ bcnt, float* __restrict__ acc,
    int NBKT, int GP) {
  const int b = blockIdx.x;
  const int tid = threadIdx.x;
  if (b >= 132) {                                 // zeroing blocks
    int base = (b - 132) * 4096 + tid;
    #pragma unroll
    for (int j = 0; j < 16; ++j) {
      int i = base + j * 256;
      if (i < NBKT) bcnt[i] = 0;
      else if (i < NBKT + GP) acc[i - NBKT] = 0.f;
    }
    return;
  }
  __shared__ int s_cnt;
  if (tid == 0) s_cnt = 0;
  __syncthreads();
  if (b >= 4) {                                   // swizzle blocks, self-probe W dtype
    const void* Wraw = (b < 68) ? W1 : W2;
    unsigned short* out = (b < 68) ? w1s : w2s;
    const unsigned short* Wu = (const unsigned short*)Wraw;
    int c = 0;
    for (int i = tid; i < 512; i += 256) {
      int e = (Wu[i] >> 7) & 0xFF;
      if (e < 96 || e > 159) c++;                 // fp32 halves look wild as bf16
    }
    atomicAdd(&s_cnt, c);
    __syncthreads();
    const int wf32 = s_cnt > 64;
    int u = ((b - 4) & 63) * 256 + tid;           // 0..16383
    int j = u & 7, lane = (u >> 3) & 63, blk = u >> 9;
    int cc = blk >> 3, t = blk & 7;
    int quad = lane >> 4, col = lane & 15;
    int k = cc * 32 + quad * 8 + j;
    int n = t * 16 + col;
    out[u] = wf32 ? f2bf(((const float*)Wraw)[k * 128 + n])
                  : ((const unsigned short*)Wraw)[k * 128 + n];
    return;
  }
  int cnt = 0;
  if (b == 1) {  // int width: high words of int64 positives are all zero
    for (int i = tid; i < 4096; i += 256)
      if (ei[2 * i + 1] == 0) cnt++;
    atomicAdd(&s_cnt, cnt);
    __syncthreads();
    if (tid == 0) flags[1] = (s_cnt > 2048) ? 1 : 0;
    return;
  }
  const unsigned short* p; int n; int fi;
  if (b == 0)      { p = xu;  n = 16384; fi = 0; }
  else if (b == 2) { p = b1u; n = 128;   fi = 4; }
  else             { p = b2u; n = 128;   fi = 5; }
  for (int i = tid; i < n; i += 256) {
    int e = (p[i] >> 7) & 0xFF;
    if (e < 96 || e > 159) cnt++;
  }
  atomicAdd(&s_cnt, cnt);
  __syncthreads();
  if (tid == 0) flags[fi] = (s_cnt * 8 > n) ? 1 : 0;
}

// ---------- shared GEMM body (W pre-swizzled; LDS-staged coalesced C-store) ----------
__device__ __forceinline__ void gemm_body(const void* __restrict__ X,
                                          const unsigned short* __restrict__ Wsw,
                                          unsigned short* __restrict__ XWb, int N,
                                          int xf32, int row0,
                                          unsigned short* Wl, unsigned short* Xl) {
  const int tid = threadIdx.x;
  for (int v = tid; v < 2048; v += 256)           // W: linear conflict-free copy
    ((short8*)Wl)[v] = ((const short8*)Wsw)[v];
  for (int v = tid; v < 2048; v += 256) {         // X: 64 rows x 128, bf16, pad +8
    int r = v >> 5, k4 = (v & 31) * 4;
    int row = row0 + r;
    ushort4 u = make_ushort4(0, 0, 0, 0);
    if (row < N) {
      long long gi = (long long)row * 128 + k4;
      if (xf32) {
        float4 xv = *(const float4*)&((const float*)X)[gi];
        u.x = f2bf(xv.x); u.y = f2bf(xv.y); u.z = f2bf(xv.z); u.w = f2bf(xv.w);
      } else {
        u = *(const ushort4*)&((const unsigned short*)X)[gi];
      }
    }
    *(ushort4*)&Xl[r * 136 + k4] = u;
  }
  __syncthreads();
  const int w = tid >> 6, lane = tid & 63;
  const int quad = lane >> 4, col = lane & 15;
  float4v acc[8];
  #pragma unroll
  for (int t = 0; t < 8; ++t) acc[t] = (float4v){0.f, 0.f, 0.f, 0.f};
  #pragma unroll
  for (int c = 0; c < 4; ++c) {
    short8 a = *(const short8*)&Xl[(w * 16 + col) * 136 + c * 32 + quad * 8];
    #pragma unroll
    for (int t = 0; t < 8; ++t) {
      short8 b = *(const short8*)&Wl[((c * 8 + t) * 64 + lane) * 8];
      acc[t] = __builtin_amdgcn_mfma_f32_16x16x32_bf16(a, b, acc[t], 0, 0, 0);
    }
  }
  // C-store via own 16-row LDS region, then coalesced 16-B copy-out
  #pragma unroll
  for (int t = 0; t < 8; ++t) {
    #pragma unroll
    for (int r = 0; r < 4; ++r)
      Xl[(w * 16 + quad * 4 + r) * 136 + t * 16 + col] = f2bf(acc[t][r]);
  }
  __syncthreads();
  for (int v = tid; v < 1024; v += 256) {
    int r = v >> 4, ck = (v & 15) * 8;
    int row = row0 + r;
    if (row < N)
      *(short8*)&XWb[(long long)row * 128 + ck] = *(const short8*)&Xl[r * 136 + ck];
  }
}

// ---------- 1. fused: scatterA (blocks < SA) + gemm1 (blocks >= SA) ----------
__global__ __launch_bounds__(256) void scatA_gemm1_k(const int* __restrict__ ei,
    int* __restrict__ bcnt, int2* __restrict__ tmp, int E, int SA,
    const void* __restrict__ X, const unsigned short* __restrict__ Wsw,
    unsigned short* __restrict__ XWb, int N,
    const int* __restrict__ flags, int NBKT) {
  __shared__ __align__(16) char smem[50688];
  const int tid = threadIdx.x;
  if ((int)blockIdx.x >= SA) {                    // gemm1 blocks
    unsigned short* Wl = (unsigned short*)smem;           // 32 KB
    unsigned short* Xl = (unsigned short*)(smem + 32768); // 17.4 KB
    gemm_body(X, Wsw, XWb, N, flags[0], ((int)blockIdx.x - SA) * 64, Wl, Xl);
    return;
  }
  // ---- scatterA body ----
  int2* stage = (int2*)smem;                      // 32 KB
  int* hist  = (int*)(smem + 32768);
  int* off   = hist + 256;
  int* cnt2  = off + 256;
  int* gbase = cnt2 + 256;
  int* wsum  = gbase + 256;
  hist[tid] = 0; cnt2[tid] = 0;
  __syncthreads();
  const int base = blockIdx.x * 4096;
  const int i64 = flags[1];
  int rs[16], rd[16];
  #pragma unroll
  for (int j = 0; j < 16; ++j) {
    int e = base + j * 256 + tid;
    if (e < E) {
      int s, d;
      if (i64) { s = ei[2 * e]; d = ei[2 * (E + e)]; }
      else     { s = ei[e];     d = ei[E + e]; }
      rs[j] = s; rd[j] = d;
      atomicAdd(&hist[d >> SPAN_SHIFT], 1);
    } else rd[j] = -1;
  }
  __syncthreads();
  {
    int lane = tid & 63, w = tid >> 6;
    int v = hist[tid], inc = v;
    #pragma unroll
    for (int o = 1; o < 64; o <<= 1) { int n = __shfl_up(inc, o, 64); if (lane >= o) inc += n; }
    if (lane == 63) wsum[w] = inc;
    __syncthreads();
    int pre = 0;
    #pragma unroll
    for (int k = 0; k < 4; ++k) if (k < w) pre += wsum[k];
    off[tid] = pre + inc - v;
  }
  __syncthreads();
  #pragma unroll
  for (int j = 0; j < 16; ++j) {
    if (rd[j] >= 0) {
      int b = rd[j] >> SPAN_SHIFT;
      int r = atomicAdd(&cnt2[b], 1);
      int2 rec; rec.x = rs[j]; rec.y = rd[j];
      stage[off[b] + r] = rec;
    }
  }
  if (tid < NBKT && hist[tid] > 0)
    gbase[tid] = tid * BCAP + atomicAdd(&bcnt[tid], hist[tid]);
  __syncthreads();
  const int total = off[255] + hist[255];
  for (int i = tid; i < total; i += 256) {
    int2 rec = stage[i];
    int b = rec.y >> SPAN_SHIFT;
    tmp[gbase[b] + (i - off[b])] = rec;
  }
}

// ---------- generic GEMM (xmode: 1 = fp32 input, 2 = bf16 input) ----------
__global__ __launch_bounds__(256) void gemm_k(const void* __restrict__ X,
                                              const unsigned short* __restrict__ Wsw,
                                              unsigned short* __restrict__ XWb, int N,
                                              int xmode) {
  __shared__ __align__(16) unsigned short Wl[16384];
  __shared__ __align__(16) unsigned short Xl[64 * 136];
  gemm_body(X, Wsw, XWb, N, (xmode == 1) ? 1 : 0, blockIdx.x * 64, Wl, Xl);
}

// ---------- 2. scatB (1024 threads): hist -> rowptr+dinv -> place ----------
__global__ __launch_bounds__(1024) void scatB_k(const int2* __restrict__ tmp,
    const int* __restrict__ bcnt, int* __restrict__ rowptr,
    float* __restrict__ dinv, int* __restrict__ spk, int N, int NBKT, int E) {
  __shared__ int hist[256];
  __shared__ int pfx[256];
  __shared__ int cur[256];
  __shared__ int ws[4];
  const int tid = threadIdx.x;
  const int b = blockIdx.x;
  const int lane = tid & 63, w = tid >> 6;
  // global prefix over bucket counts (first 256 threads; 196 ints, L2-hot)
  int c = (tid < 256 && tid < NBKT) ? bcnt[tid] : 0;
  if (tid < 256) hist[tid] = 0;
  {
    int inc = c;
    #pragma unroll
    for (int o = 1; o < 64; o <<= 1) { int n = __shfl_up(inc, o, 64); if (lane >= o) inc += n; }
    if (tid < 256 && lane == 63) ws[w] = inc;
    __syncthreads();
    if (tid < 256) {
      int pre = 0;
      #pragma unroll
      for (int k = 0; k < 4; ++k) if (k < w) pre += ws[k];
      pfx[tid] = pre + inc - c;
    }
  }
  __syncthreads();
  const int bbase = pfx[b];
  const int cnt = bcnt[b];
  const int2* src = tmp + (long long)b * BCAP;
  for (int i = tid; i < cnt; i += 1024)
    atomicAdd(&hist[src[i].y & 255], 1);
  __syncthreads();
  // node-level scan (first 256 threads)
  int v = (tid < 256) ? hist[tid] : 0;
  {
    int inc = v;
    #pragma unroll
    for (int o = 1; o < 64; o <<= 1) { int n = __shfl_up(inc, o, 64); if (lane >= o) inc += n; }
    if (tid < 256 && lane == 63) ws[w] = inc;
    __syncthreads();
    if (tid < 256) {
      int pre = 0;
      #pragma unroll
      for (int k = 0; k < 4; ++k) if (k < w) pre += ws[k];
      const int start = bbase + pre + inc - v;
      int node = (b << SPAN_SHIFT) + tid;
      if (node < N) {
        rowptr[node] = start;
        dinv[node] = rsqrtf((float)(v + 1));   // +1 self-loop
      }
      cur[tid] = start;
    }
  }
  if (b == 0 && tid == 0) rowptr[N] = E;
  __syncthreads();
  for (int i = tid; i < cnt; i += 1024) {   // place (src-only payload)
    int2 rec = src[i];
    int pos = atomicAdd(&cur[rec.y & 255], 1);
    spk[pos] = rec.x;
  }
}

// ---------- 3. aggregate: quarter-wave gathers + cooperative index preload ----------
__global__ __launch_bounds__(256) void aggregate_k(const unsigned short* __restrict__ XWb,
    const int* __restrict__ rowptr, const int* __restrict__ spk,
    const float* __restrict__ dinv, const void* __restrict__ bias_raw, int bias_fi,
    void* __restrict__ H, int N, int relu, int out_bf16,
    const int* __restrict__ flags) {
  int wid = (blockIdx.x * 256 + threadIdx.x) >> 6;  // one wave per node
  if (wid >= N) return;
  const int lane = threadIdx.x & 63;
  const int q = lane >> 4;           // quarter: which edge of the group
  const int fl = (lane & 15) * 8;    // 8 features per lane
  const int beg = rowptr[wid], end = rowptr[wid + 1];
  const int deg = end - beg;
  const float di = dinv[wid];
  float a[8];
  #pragma unroll
  for (int j = 0; j < 8; ++j) a[j] = 0.f;
  for (int base = 0; base < deg; base += 64) {
    const int rem = min(deg - base, 64);              // wave-uniform
    const int li = base + lane;
    const int sil = spk[beg + min(li, deg - 1)];      // ONE coalesced load (clamped)
    const float wl = (li < deg) ? dinv[sil] : 0.f;    // ONE gather
    const int ngroups = (rem + 3) >> 2;               // wave-uniform, <= 16
    int g = 0;
    for (; g + 4 <= ngroups; g += 4) {                // 16 edges per iteration
      int e0 = (g + 0) * 4 + q, e1 = (g + 1) * 4 + q;
      int e2 = (g + 2) * 4 + q, e3 = (g + 3) * 4 + q;
      int   s0 = __shfl(sil, e0, 64), s1 = __shfl(sil, e1, 64);
      int   s2 = __shfl(sil, e2, 64), s3 = __shfl(sil, e3, 64);
      float w0 = __shfl(wl, e0, 64),  w1 = __shfl(wl, e1, 64);
      float w2 = __shfl(wl, e2, 64),  w3 = __shfl(wl, e3, 64);
      short8 u0 = *(const short8*)&XWb[(long long)s0 * 128 + fl];
      short8 u1 = *(const short8*)&XWb[(long long)s1 * 128 + fl];
      short8 u2 = *(const short8*)&XWb[(long long)s2 * 128 + fl];
      short8 u3 = *(const short8*)&XWb[(long long)s3 * 128 + fl];
      #pragma unroll
      for (int j = 0; j < 8; ++j)
        a[j] += w0 * bf2f((unsigned short)u0[j]) + w1 * bf2f((unsigned short)u1[j])
              + w2 * bf2f((unsigned short)u2[j]) + w3 * bf2f((unsigned short)u3[j]);
    }
    if (g + 2 <= ngroups) {                           // 8-edge tail
      int e0 = (g + 0) * 4 + q, e1 = (g + 1) * 4 + q;
      int   s0 = __shfl(sil, e0, 64), s1 = __shfl(sil, e1, 64);
      float w0 = __shfl(wl, e0, 64),  w1 = __shfl(wl, e1, 64);
      short8 u0 = *(const short8*)&XWb[(long long)s0 * 128 + fl];
      short8 u1 = *(const short8*)&XWb[(long long)s1 * 128 + fl];
      #pragma unroll
      for (int j = 0; j < 8; ++j)
        a[j] += w0 * bf2f((unsigned short)u0[j]) + w1 * bf2f((unsigned short)u1[j]);
      g += 2;
    }
    if (g < ngroups) {                                // 4-edge tail
      int e0 = g * 4 + q;
      int   s0 = __shfl(sil, e0, 64);
      float w0 = __shfl(wl, e0, 64);
      short8 u0 = *(const short8*)&XWb[(long long)s0 * 128 + fl];
      #pragma unroll
      for (int j = 0; j < 8; ++j)
        a[j] += w0 * bf2f((unsigned short)u0[j]);
    }
  }
  #pragma unroll
  for (int j = 0; j < 8; ++j) {       // cross-quarter reduce
    a[j] += __shfl_xor(a[j], 16, 64);
    a[j] += __shfl_xor(a[j], 32, 64);
  }
  if (q == 0) {
    short8 su = *(const short8*)&XWb[(long long)wid * 128 + fl];
    float d2 = di * di;
    float o[8];
    #pragma unroll
    for (int j = 0; j < 8; ++j)
      o[j] = di * a[j] + d2 * bf2f((unsigned short)su[j]);
    if (bias_fi >= 0) {
      if (flags[bias_fi]) {
        const float* bf = (const float*)bias_raw;
        float4 b0 = *(const float4*)&bf[fl];
        float4 b1 = *(const float4*)&bf[fl + 4];
        o[0] += b0.x; o[1] += b0.y; o[2] += b0.z; o[3] += b0.w;
        o[4] += b1.x; o[5] += b1.y; o[6] += b1.z; o[7] += b1.w;
      } else {
        const unsigned short* bu = (const unsigned short*)bias_raw;
        #pragma unroll
        for (int j = 0; j < 8; ++j) o[j] += bf2f(bu[fl + j]);
      }
    }
    if (relu) {
      #pragma unroll
      for (int j = 0; j < 8; ++j) o[j] = fmaxf(o[j], 0.f);
    }
    if (out_bf16) {
      short8 uo;
      #pragma unroll
      for (int j = 0; j < 8; ++j) uo[j] = (short)f2bf(o[j]);
      *(short8*)&((unsigned short*)H)[(long long)wid * 128 + fl] = uo;
    } else {
      float* Hf = (float*)H;
      *(float4*)&Hf[(long long)wid * 128 + fl]     = make_float4(o[0], o[1], o[2], o[3]);
      *(float4*)&Hf[(long long)wid * 128 + fl + 4] = make_float4(o[4], o[5], o[6], o[7]);
    }
  }
}

// ---------- 4a. pool phase A (H is bf16) ----------
__global__ __launch_bounds__(256) void pool_partial_k(const unsigned short* __restrict__ H,
    const int* __restrict__ batch, float* __restrict__ acc, int N,
    const int* __restrict__ flags) {
  const int i64 = flags[1];
  const int lane = threadIdx.x & 63;
  const int w = threadIdx.x >> 6;
  const int chunk = (N + gridDim.x - 1) / gridDim.x;
  const int bstart = blockIdx.x * chunk;
  const int bend = min(bstart + chunk, N);
  const int sub = (chunk + 3) / 4;
  const int s = bstart + w * sub;
  const int e = min(s + sub, bend);
  if (s >= e) return;
  float ax = 0.f, ay = 0.f;
  int curg = i64 ? batch[2 * s] : batch[s];
  for (int n = s; n < e; ++n) {
    int g = i64 ? batch[2 * n] : batch[n];
    if (g != curg) {
      atomicAdd(&acc[curg * 128 + lane * 2], ax);
      atomicAdd(&acc[curg * 128 + lane * 2 + 1], ay);
      ax = ay = 0.f; curg = g;
    }
    ushort2 v = *(const ushort2*)&H[(long long)n * 128 + lane * 2];
    ax += bf2f(v.x); ay += bf2f(v.y);
  }
  atomicAdd(&acc[curg * 128 + lane * 2], ax);
  atomicAdd(&acc[curg * 128 + lane * 2 + 1], ay);
}

// ---------- 4b. pool finalize ----------
__global__ __launch_bounds__(128) void pool_final_k(const float* __restrict__ acc,
    const int* __restrict__ batch, const void* __restrict__ B2raw,
    float* __restrict__ out, int N, const int* __restrict__ flags) {
  __shared__ int sb[2];
  int g = blockIdx.x;
  int i64 = flags[1];
  if (threadIdx.x < 2) {
    int target = g + threadIdx.x;
    int lo = 0, hi = N;
    while (lo < hi) {
      int mid = (lo + hi) >> 1;
      int bv = i64 ? batch[2 * mid] : batch[mid];
      if (bv < target) lo = mid + 1; else hi = mid;
    }
    sb[threadIdx.x] = lo;
  }
  __syncthreads();
  int cnt = sb[1] - sb[0];
  int f = threadIdx.x;
  float b2 = flags[5] ? ((const float*)B2raw)[f]
                      : bf2f(((const unsigned short*)B2raw)[f]);
  float res = 0.f;
  if (cnt > 0) res = acc[g * 128 + f] / (float)cnt + b2;
  out[g * 128 + f] = res;
}

extern "C" void kernel_launch(void* const* d_in, const int* in_sizes, int n_in,
                              void* d_out, int out_size, void* d_ws, size_t ws_size,
                              hipStream_t stream) {
  const int N = in_sizes[0] / 128;   // 50000
  const int E = in_sizes[1] / 2;     // 800000
  const int G = out_size / 128;      // 64
  const int NB = (N + 255) >> SPAN_SHIFT;  // dst buckets (196), <=256
  const int GB = (N + 63) / 64;            // gemm blocks
  const int SA = (E + 4095) / 4096;        // scatterA blocks
  const int GP = G * 128;
  const int ZB = (NB + GP + 4095) / 4096;  // zeroing blocks

  const void* X  = d_in[0];
  const int*  EI = (const int*)d_in[1];
  const int*  BA = (const int*)d_in[2];
  const void* W1 = d_in[3];
  const void* B1 = d_in[4];
  const void* W2 = d_in[5];
  const void* B2 = d_in[6];
  float* OUT = (float*)d_out;

  char* ws = (char*)d_ws;
  size_t o = 0;
  auto alloc = [&](size_t b) { size_t r = o; o += (b + 255) & ~(size_t)255; return r; };
  int*   flags  = (int*)(ws + alloc(256));
  unsigned short* w1s = (unsigned short*)(ws + alloc(16384 * 2));  // pre-swizzled bf16
  unsigned short* w2s = (unsigned short*)(ws + alloc(16384 * 2));
  float* acc    = (float*)(ws + alloc((size_t)GP * 4));
  int*   bcnt   = (int*)(ws + alloc(256 * 4));
  int*   rowptr = (int*)(ws + alloc((size_t)(N + 1) * 4));
  int*   spk    = (int*)(ws + alloc((size_t)E * 4));      // src-only payload
  float* dinv   = (float*)(ws + alloc((size_t)N * 4));
  unsigned short* xwb = (unsigned short*)(ws + alloc((size_t)N * 128 * 2));
  char*  hreg   = ws + alloc((size_t)N * 128 * 4);  // 25.6 MB multi-use region
  unsigned short* h1b = (unsigned short*)hreg;      // layer-1 H, bf16 (12.8 MB)
  unsigned short* h2b = (unsigned short*)hreg;      // layer-2 H, bf16 (12.8 MB)
  int2*  tmp    = (int2*)hreg;                      // bucket regions 12.85 MB; dead before aggregate1

  // 1. probes + W pre-swizzle + zeroing (one launch)
  detect_swz_zero_k<<<132 + ZB, 256, 0, stream>>>(
      (const unsigned short*)X, EI,
      (const unsigned short*)B1, (const unsigned short*)B2,
      W1, W2, w1s, w2s, flags, bcnt, acc, NB, GP);
  // 2. fused scatterA + gemm1
  scatA_gemm1_k<<<SA + GB, 256, 0, stream>>>(EI, bcnt, tmp, E, SA,
                                             X, w1s, xwb, N, flags, NB);
  // 3. CSR finish (single merged kernel, 1024 threads)
  scatB_k<<<NB, 1024, 0, stream>>>(tmp, bcnt, rowptr, dinv, spk, N, NB, E);

  dim3 agrid((N * 64 + 255) / 256);
  // layer 1 aggregate (bf16 out; tmp is dead now)
  aggregate_k<<<agrid, 256, 0, stream>>>(xwb, rowptr, spk, dinv, B1, 4,
                                         h1b, N, 1, 1, flags);
  // layer 2
  gemm_k<<<GB, 256, 0, stream>>>(h1b, w2s, xwb, N, 2);
  aggregate_k<<<agrid, 256, 0, stream>>>(xwb, rowptr, spk, dinv, (const void*)nullptr, -1,
                                         h2b, N, 0, 1, flags);
  // pool (two launches — fused variants regress: barrier r9, fence r18)
  pool_partial_k<<<512, 256, 0, stream>>>(h2b, BA, acc, N, flags);
  pool_final_k<<<G, 128, 0, stream>>>(acc, BA, B2, OUT, N, flags);
}